// Round 1
// baseline (174.146 us; speedup 1.0000x reference)
//
#include <hip/hip_runtime.h>
#include <stdint.h>

// Gemma4PatchEmbed round 8: 32-row M-tiles, 2 blocks/CU for cross-phase overlap.
// bpack: w_proj fp32 -> bf16 packed fragment-linear (1KB per 32n x 16k chunk).
// fused: block = 32 M-rows x 768 N, 512 thr, grid 512 (2 blocks/CU; LDS 49.7KB).
//        phase 1: pixels -> bf16 -> LDS A (stride 776). ONE __syncthreads.
//        phase 2: two-buffer register rotation, 3x v_mfma_f32_32x32x16_bf16
//        per k16 per wave; fragments issued ~1 k16-pair (~775 cyc) before use.
//        Fused pos-gather epilogue.
// Rationale: round-7 (64-row, 1 block/CU) was latency-bound: MfmaUtil 12.4%,
// VALUBusy 10.5%, Occupancy 18% -- three serial ~8us phases with no overlap.
// 2 blocks/CU overlaps block A's GEMM with block B's HBM stage/epilogue and
// doubles waves/SIMD to 4. __launch_bounds__(512,4) caps regs at 128
// (need ~110: 48 acc + 32 frags + addressing) so both blocks fit.

typedef __attribute__((ext_vector_type(8))) short bfrag_t;        // MFMA A/B operand
typedef __attribute__((ext_vector_type(16))) float f16acc;         // 32x32 MFMA C/D
typedef __attribute__((ext_vector_type(8))) unsigned short u16x8;
typedef __attribute__((ext_vector_type(4))) unsigned short u16x4;

#define V_POS 10240
#define RSA 776     // LDS A row stride in shorts: +4 dword-banks/row -> b128 floor

__device__ __forceinline__ unsigned short f2bf(float f) {
    unsigned int u = __float_as_uint(f);
    u += 0x7fffu + ((u >> 16) & 1u);          // RNE fp32 -> bf16
    return (unsigned short)(u >> 16);
}

// ---------------------------------------------------------------------------
// Kernel 1: pack w_proj into fragment-linear bf16.
// chunk (n32, k16) = 1024 B; lane holds w_proj[n32*32 + (lane&31)]
// [k16*16 + (lane>>5)*8 + j], j<8. 288 blocks x 256 thr.
// ---------------------------------------------------------------------------
__global__ __launch_bounds__(256) void bpack_kernel(
    const float* __restrict__ wp, unsigned short* __restrict__ Bp)
{
    int u     = blockIdx.x * 256 + threadIdx.x;   // 0..73727
    int chunk = u >> 6;                           // 0..1151
    int lane  = u & 63;
    int n32   = chunk / 48;
    int k16   = chunk - n32 * 48;
    int n     = (n32 << 5) + (lane & 31);
    int k     = (k16 << 4) + ((lane >> 5) << 3);
    const float* s = wp + (size_t)n * 768 + k;
    float4 v0 = *(const float4*)s;
    float4 v1 = *(const float4*)(s + 4);
    u16x8 o;
    o[0] = f2bf(v0.x); o[1] = f2bf(v0.y); o[2] = f2bf(v0.z); o[3] = f2bf(v0.w);
    o[4] = f2bf(v1.x); o[5] = f2bf(v1.y); o[6] = f2bf(v1.z); o[7] = f2bf(v1.w);
    *(u16x8*)(Bp + (size_t)chunk * 512 + (lane << 3)) = o;
}

// ---------------------------------------------------------------------------
// Kernel 2: fused patch-extract + GEMM + pos-embed. 512 blocks x 512 threads.
// Block = 32 patch rows (one image patch-row py) x all 768 output cols.
// ---------------------------------------------------------------------------
__global__ __launch_bounds__(512, 4) void fused_kernel(
    const float* __restrict__ px, const unsigned short* __restrict__ Bp,
    const int* __restrict__ pos_ids, const unsigned int* __restrict__ pad_in,
    const float* __restrict__ pos_table, float* __restrict__ out)
{
    __shared__ unsigned short As[32 * RSA];   // 49664 B -> 2 blocks/CU

    const int tid  = threadIdx.x;
    const int wave = tid >> 6;                // 0..7
    const int lane = tid & 63;
    const int bid  = blockIdx.x;
    const int m0   = bid << 5;                // 32 patch rows per block
    const int img  = bid >> 5;
    const int prow = bid & 31;                // image pixel rows 16*prow .. +16

    // ---------------- phase 1: pixels -> bf16 A-tile in LDS ----------------
    // 32 patches x 768 k = 6144 float4 per block; 12 per thread.
    const float* base = px + ((size_t)img * 3 * 512 + (size_t)prow * 16) * 512;
#pragma unroll 6
    for (int it = 0; it < 12; ++it) {
        int idx = it * 512 + tid;             // 0..6143
        int c   = idx >> 11;                  // 2048 f4 per channel (16 rows)
        int rem = idx & 2047;
        int hl  = rem >> 7;                   // 0..15 image row within region
        int w4  = rem & 127;
        float4 v = *(const float4*)(base + (size_t)c * 262144 + hl * 512 + (w4 << 2));
        int r = w4 >> 2;                      // A row = patch x-index
        int k = (c << 8) + (hl << 4) + ((w4 & 3) << 2);
        u16x4 o;
        o[0] = f2bf(2.f * v.x - 1.f);
        o[1] = f2bf(2.f * v.y - 1.f);
        o[2] = f2bf(2.f * v.z - 1.f);
        o[3] = f2bf(2.f * v.w - 1.f);
        *(u16x4*)&As[r * RSA + k] = o;
    }
    __syncthreads();                          // the only barrier in the kernel

    // padding-bool upload-width probe (256 B, in-bounds either way)
    const bool u8mode = __any(pad_in[lane] > 1u);

    // ---------------- phase 2: software-pipelined barrier-free loop --------
    const unsigned short* afrag = As + (size_t)(lane & 31) * RSA + ((lane >> 5) << 3);
    const unsigned short* bbase = Bp + (size_t)(wave * 3) * 48 * 512 + (lane << 3);

    f16acc acc[3] = {};

    bfrag_t aC, bC0, bC1, bC2;                // buffer C: even k16
    bfrag_t aN, bN0, bN1, bN2;                // buffer N: odd  k16

#define LDA(k, r0) { r0 = *(const bfrag_t*)(afrag + ((k) << 4)); }
#define LDB(k, r0, r1, r2) { const unsigned short* bk_ = bbase + (size_t)(k) * 512; \
        r0 = *(const bfrag_t*)(bk_);                                          \
        r1 = *(const bfrag_t*)(bk_ + 48 * 512);                               \
        r2 = *(const bfrag_t*)(bk_ + 96 * 512); }
#define MFMA3(a0, b0, b1, b2)                                                 \
        acc[0] = __builtin_amdgcn_mfma_f32_32x32x16_bf16(a0, b0, acc[0], 0, 0, 0); \
        acc[1] = __builtin_amdgcn_mfma_f32_32x32x16_bf16(a0, b1, acc[1], 0, 0, 0); \
        acc[2] = __builtin_amdgcn_mfma_f32_32x32x16_bf16(a0, b2, acc[2], 0, 0, 0);

    LDA(0, aC); LDB(0, bC0, bC1, bC2);        // prologue: k16 = 0, 1 in regs
    LDA(1, aN); LDB(1, bN0, bN1, bN2);

    for (int k16 = 0; k16 < 48; k16 += 2) {
        // consume C (k16), refill C with k16+2 (issued ~1 k16-pair before use)
        MFMA3(aC, bC0, bC1, bC2);
        if (k16 + 2 < 48) { LDA(k16 + 2, aC); LDB(k16 + 2, bC0, bC1, bC2); }
        // consume N (k16+1), refill N with k16+3
        MFMA3(aN, bN0, bN1, bN2);
        if (k16 + 3 < 48) { LDA(k16 + 3, aN); LDB(k16 + 3, bN0, bN1, bN2); }
    }
#undef LDA
#undef LDB
#undef MFMA3

    // ---- epilogue: 32x32 C/D layout col=lane&31, row=(r&3)+8*(r>>2)+4*(lane>>5)
    const unsigned char* pad8 = (const unsigned char*)pad_in;
    const int cl  = lane & 31;
    const int h4  = (lane >> 5) << 2;
#pragma unroll 4
    for (int r = 0; r < 16; ++r) {
        int row = (r & 3) + ((r >> 2) << 3) + h4;
        int gm  = m0 + row;
        int xid = pos_ids[2 * gm];
        int yid = pos_ids[2 * gm + 1];
        xid = xid < 0 ? 0 : xid;
        yid = yid < 0 ? 0 : yid;
        bool p = u8mode ? (pad8[gm] != 0) : (pad_in[gm] != 0u);
        const float* t0 = pos_table + (size_t)xid * 768;
        const float* t1 = pos_table + (size_t)(V_POS + yid) * 768;
        float* orow = out + (size_t)gm * 768;
#pragma unroll
        for (int nt = 0; nt < 3; ++nt) {
            int col = wave * 96 + (nt << 5) + cl;
            float pos = p ? 0.f : (t0[col] + t1[col]);
            orow[col] = acc[nt][r] + pos;
        }
    }
}

extern "C" void kernel_launch(void* const* d_in, const int* in_sizes, int n_in,
                              void* d_out, int out_size, void* d_ws, size_t ws_size,
                              hipStream_t stream) {
    const float*        px  = (const float*)d_in[0];        // (16,3,512,512)
    const float*        wp  = (const float*)d_in[1];        // (768,768)
    const float*        pt  = (const float*)d_in[2];        // (2,10240,768)
    const int*          pid = (const int*)d_in[3];          // (16,1024,2)
    const unsigned int* pad = (const unsigned int*)d_in[4]; // (16,1024) bool

    unsigned short* Bp = (unsigned short*)d_ws;             // 1.18 MB packed bf16

    bpack_kernel<<<288, 256, 0, stream>>>(wp, Bp);
    fused_kernel<<<512, 512, 0, stream>>>(px, Bp, pid, pad, pt, (float*)d_out);
}